// Round 2
// baseline (2019.907 us; speedup 1.0000x reference)
//
#include <hip/hip_runtime.h>
#include <hip/hip_bf16.h>
#include <math.h>

// Problem constants. Inputs/outputs are fp32 (reference dtype); MFMA compute
// uses bf16 hi+lo compensated splitting for fp32-accurate logits.
#define BB    4
#define NV    4096
#define NT    1024
#define VDIM  1024
#define TDIM  1024
#define HEADS 8
#define DHEAD 128   // TDIM / HEADS

typedef __bf16 bf16x8 __attribute__((ext_vector_type(8)));
typedef float  f32x4  __attribute__((ext_vector_type(4)));

__device__ __forceinline__ bf16x8 load8(const __bf16* p) {
    return *reinterpret_cast<const bf16x8*>(p);
}
__device__ __forceinline__ void store8(__bf16* p, bf16x8 v) {
    *reinterpret_cast<bf16x8*>(p) = v;
}
// Load 8 fp32, split each into bf16 hi + bf16 lo (x = hi + lo + O(2^-18 x)).
__device__ __forceinline__ void split8(const float* __restrict__ p,
                                       bf16x8& hi, bf16x8& lo) {
    const f32x4 v0 = *reinterpret_cast<const f32x4*>(p);
    const f32x4 v1 = *reinterpret_cast<const f32x4*>(p + 4);
#pragma unroll
    for (int j = 0; j < 4; j++) {
        const __bf16 h0 = (__bf16)v0[j];
        hi[j] = h0; lo[j] = (__bf16)(v0[j] - (float)h0);
        const __bf16 h1 = (__bf16)v1[j];
        hi[4 + j] = h1; lo[4 + j] = (__bf16)(v1[j] - (float)h1);
    }
}

// ---------------------------------------------------------------------------
// Kernel 1: vc = visual @ W^T  (fp32 in, fp32-accurate via 3-MFMA hi/lo).
// vc stored as bf16 hi+lo pair so QK^T can rebuild fp32-exact logits.
// 128x128 block tile, 4 waves of 64x64. MFMA 16x16x32 bf16.
// A[m=lane&15][k=quad*8+j]; B[n=lane&15][k=quad*8+j]; C/D col=lane&15,
// row=quad*4+reg (m89-verified layouts).
// ---------------------------------------------------------------------------
__global__ __launch_bounds__(256) void gemm1_kernel(
    const float* __restrict__ visual,   // [B*NV, VDIM]
    const float* __restrict__ W,        // [TDIM, VDIM]
    __bf16* __restrict__ vc_hi,         // [B*NV, TDIM]
    __bf16* __restrict__ vc_lo)
{
    const int lane = threadIdx.x & 63;
    const int wave = threadIdx.x >> 6;
    const int wm = wave >> 1, wn = wave & 1;
    const int m0 = blockIdx.y * 128 + wm * 64;
    const int n0 = blockIdx.x * 128 + wn * 64;
    const int lrow = lane & 15;
    const int lk8  = (lane >> 4) * 8;

    f32x4 acc[4][4];
#pragma unroll
    for (int i = 0; i < 4; i++)
#pragma unroll
        for (int j = 0; j < 4; j++) acc[i][j] = (f32x4){0.f, 0.f, 0.f, 0.f};

    for (int k0 = 0; k0 < VDIM; k0 += 32) {
        bf16x8 bh[4], bl[4];
#pragma unroll
        for (int nt = 0; nt < 4; nt++)
            split8(W + (size_t)(n0 + nt * 16 + lrow) * VDIM + k0 + lk8, bh[nt], bl[nt]);
#pragma unroll
        for (int mt = 0; mt < 4; mt++) {
            bf16x8 ah, al;
            split8(visual + (size_t)(m0 + mt * 16 + lrow) * VDIM + k0 + lk8, ah, al);
#pragma unroll
            for (int nt = 0; nt < 4; nt++) {
                acc[mt][nt] = __builtin_amdgcn_mfma_f32_16x16x32_bf16(ah, bh[nt], acc[mt][nt], 0, 0, 0);
                acc[mt][nt] = __builtin_amdgcn_mfma_f32_16x16x32_bf16(ah, bl[nt], acc[mt][nt], 0, 0, 0);
                acc[mt][nt] = __builtin_amdgcn_mfma_f32_16x16x32_bf16(al, bh[nt], acc[mt][nt], 0, 0, 0);
            }
        }
    }

    const int r0 = (lane >> 4) * 4;
#pragma unroll
    for (int mt = 0; mt < 4; mt++)
#pragma unroll
        for (int nt = 0; nt < 4; nt++)
#pragma unroll
            for (int r = 0; r < 4; r++) {
                const int row = m0 + mt * 16 + r0 + r;
                const int col = n0 + nt * 16 + lrow;
                const float v = acc[mt][nt][r];
                const __bf16 h = (__bf16)v;          // RNE
                const __bf16 lo = (__bf16)(v - (float)h);
                const size_t idx = (size_t)row * TDIM + col;
                vc_hi[idx] = h;
                vc_lo[idx] = lo;
            }
}

// ---------------------------------------------------------------------------
// Kernel 2: kT[bh][d][kv] = vc_hi[b][kv][h*128+d]  (per-head transposed K so
// PV's B-operand fragments are contiguous-in-kv). 64x64 LDS tile, +8 pad.
// ---------------------------------------------------------------------------
__global__ __launch_bounds__(256) void transpose_kernel(
    const __bf16* __restrict__ vc_hi,   // [B, NV, TDIM]
    __bf16* __restrict__ kT)            // [B*H, DHEAD, NV]
{
    __shared__ __bf16 tile[64][72];
    const int bh = blockIdx.z;
    const int b = bh >> 3, h = bh & 7;
    const int kv0 = blockIdx.x * 64;
    const int d0  = blockIdx.y * 64;
    const int t = threadIdx.x;

#pragma unroll
    for (int it = 0; it < 2; it++) {
        const int kvl = (t >> 3) + it * 32;
        const int dl  = (t & 7) * 8;
        bf16x8 v = load8(vc_hi + (size_t)(b * NV + kv0 + kvl) * TDIM + h * DHEAD + d0 + dl);
#pragma unroll
        for (int j = 0; j < 8; j++) tile[kvl][dl + j] = v[j];
    }
    __syncthreads();
#pragma unroll
    for (int it = 0; it < 2; it++) {
        const int dl  = (t >> 3) + it * 32;
        const int kvl = (t & 7) * 8;
        bf16x8 v;
#pragma unroll
        for (int j = 0; j < 8; j++) v[j] = tile[kvl + j][dl];
        store8(kT + (size_t)(bh * DHEAD + d0 + dl) * NV + kv0 + kvl, v);
    }
}

// ---------------------------------------------------------------------------
// Kernel 3: fused attention. Block = (bh, 64 q-rows); wave w owns q-rows
// [w*16, w*16+16). Logits via 3-MFMA hi/lo (fp32-accurate). Two passes:
//   pass 1: running (m, l) per q-row (butterfly over low-4 lane bits = the
//           C-layout's 16 columns per register).
//   pass 2: recompute S, p = exp(s-m)/l; write attn fp32 straight from
//           C-layout regs; bf16 p -> wave-private LDS stripe -> A-layout
//           fragments for PV (m120-verified round trip); PV from kT.
// ---------------------------------------------------------------------------
__global__ __launch_bounds__(256) void attn_kernel(
    const float* __restrict__ textual,  // [B, NT, TDIM] fp32
    const __bf16* __restrict__ vc_hi,   // [B, NV, TDIM]
    const __bf16* __restrict__ vc_lo,
    const __bf16* __restrict__ kT,      // [B*H, DHEAD, NV]
    float* __restrict__ out,            // [B, NT, TDIM] fp32
    float* __restrict__ attn)           // [B*H, NT, NV] fp32
{
    __shared__ __bf16 lds_p[64][72];    // P tile, wave-private 16-row stripes

    const int bh = blockIdx.y;
    const int b = bh >> 3, h = bh & 7;
    const int q0 = blockIdx.x * 64;
    const int lane = threadIdx.x & 63;
    const int wave = threadIdx.x >> 6;
    const int lrow = lane & 15;
    const int quad = lane >> 4;
    const int lk8  = quad * 8;
    const int qw = q0 + wave * 16;      // this wave's q base

    // Q fragments (hi/lo): A[m=lane&15][k], d=128 -> 4 k-steps of 32
    bf16x8 qh[4], ql[4];
#pragma unroll
    for (int ks = 0; ks < 4; ks++)
        split8(textual + (size_t)(b * NT + qw + lrow) * TDIM + h * DHEAD + ks * 32 + lk8,
               qh[ks], ql[ks]);

    const __bf16* khi_base = vc_hi + (size_t)b * NV * TDIM + h * DHEAD;
    const __bf16* klo_base = vc_lo + (size_t)b * NV * TDIM + h * DHEAD;

    float m_run[4], l_run[4];
#pragma unroll
    for (int r = 0; r < 4; r++) { m_run[r] = -INFINITY; l_run[r] = 0.f; }

    // ---- pass 1: running max & denom ----
    for (int kt = 0; kt < NV / 64; kt++) {
        const int kv0 = kt * 64;
        f32x4 acc[4];
#pragma unroll
        for (int c = 0; c < 4; c++) acc[c] = (f32x4){0.f, 0.f, 0.f, 0.f};
#pragma unroll
        for (int c = 0; c < 4; c++) {
            const size_t rowb = (size_t)(kv0 + c * 16 + lrow) * TDIM;
#pragma unroll
            for (int ks = 0; ks < 4; ks++) {
                bf16x8 kh = load8(khi_base + rowb + ks * 32 + lk8);
                bf16x8 kl = load8(klo_base + rowb + ks * 32 + lk8);
                acc[c] = __builtin_amdgcn_mfma_f32_16x16x32_bf16(qh[ks], kh, acc[c], 0, 0, 0);
                acc[c] = __builtin_amdgcn_mfma_f32_16x16x32_bf16(qh[ks], kl, acc[c], 0, 0, 0);
                acc[c] = __builtin_amdgcn_mfma_f32_16x16x32_bf16(ql[ks], kh, acc[c], 0, 0, 0);
            }
        }
#pragma unroll
        for (int r = 0; r < 4; r++) {
            float tm = fmaxf(fmaxf(acc[0][r], acc[1][r]), fmaxf(acc[2][r], acc[3][r]));
#pragma unroll
            for (int off = 1; off < 16; off <<= 1)
                tm = fmaxf(tm, __shfl_xor(tm, off, 64));
            const float nm = fmaxf(m_run[r], tm);
            float ps = __expf(acc[0][r] - nm) + __expf(acc[1][r] - nm) +
                       __expf(acc[2][r] - nm) + __expf(acc[3][r] - nm);
#pragma unroll
            for (int off = 1; off < 16; off <<= 1)
                ps += __shfl_xor(ps, off, 64);
            l_run[r] = l_run[r] * __expf(m_run[r] - nm) + ps;
            m_run[r] = nm;
        }
    }
    float inv_l[4];
#pragma unroll
    for (int r = 0; r < 4; r++) inv_l[r] = 1.0f / l_run[r];

    f32x4 oacc[8];
#pragma unroll
    for (int c = 0; c < 8; c++) oacc[c] = (f32x4){0.f, 0.f, 0.f, 0.f};

    float* attn_base = attn + (size_t)bh * NT * NV;
    const __bf16* kT_base = kT + (size_t)bh * DHEAD * NV;

    // ---- pass 2: recompute S, emit attn (fp32), accumulate out ----
    for (int kt = 0; kt < NV / 64; kt++) {
        const int kv0 = kt * 64;
        f32x4 acc[4];
#pragma unroll
        for (int c = 0; c < 4; c++) acc[c] = (f32x4){0.f, 0.f, 0.f, 0.f};
#pragma unroll
        for (int c = 0; c < 4; c++) {
            const size_t rowb = (size_t)(kv0 + c * 16 + lrow) * TDIM;
#pragma unroll
            for (int ks = 0; ks < 4; ks++) {
                bf16x8 kh = load8(khi_base + rowb + ks * 32 + lk8);
                bf16x8 kl = load8(klo_base + rowb + ks * 32 + lk8);
                acc[c] = __builtin_amdgcn_mfma_f32_16x16x32_bf16(qh[ks], kh, acc[c], 0, 0, 0);
                acc[c] = __builtin_amdgcn_mfma_f32_16x16x32_bf16(qh[ks], kl, acc[c], 0, 0, 0);
                acc[c] = __builtin_amdgcn_mfma_f32_16x16x32_bf16(ql[ks], kh, acc[c], 0, 0, 0);
            }
        }
        // p: fp32 -> attn directly (coalesced 64B per 16-lane group);
        // bf16 -> wave-private LDS stripe for the PV A-operand transpose.
#pragma unroll
        for (int c = 0; c < 4; c++)
#pragma unroll
            for (int r = 0; r < 4; r++) {
                const float p = __expf(acc[c][r] - m_run[r]) * inv_l[r];
                lds_p[wave * 16 + quad * 4 + r][c * 16 + lrow] = (__bf16)p;
                attn_base[(size_t)(qw + quad * 4 + r) * NV + kv0 + c * 16 + lrow] = p;
            }

        // PV: A = P (LDS, A-layout), B = K (kT, contiguous in kv).
        // Same-wave LDS RAW: compiler-inserted lgkmcnt; stripes wave-private.
#pragma unroll
        for (int kss = 0; kss < 2; kss++) {
            bf16x8 ap = load8(&lds_p[wave * 16 + lrow][kss * 32 + lk8]);
#pragma unroll
            for (int ct = 0; ct < 8; ct++) {
                bf16x8 bk = load8(kT_base + (size_t)(ct * 16 + lrow) * NV + kv0 + kss * 32 + lk8);
                oacc[ct] = __builtin_amdgcn_mfma_f32_16x16x32_bf16(ap, bk, oacc[ct], 0, 0, 0);
            }
        }
    }

    // epilogue: out[b, q, h*128+d] fp32
#pragma unroll
    for (int ct = 0; ct < 8; ct++)
#pragma unroll
        for (int r = 0; r < 4; r++) {
            const int qrow = qw + quad * 4 + r;
            const int dcol = ct * 16 + lrow;
            out[(size_t)(b * NT + qrow) * TDIM + h * DHEAD + dcol] = oacc[ct][r];
        }
}

// ---------------------------------------------------------------------------
extern "C" void kernel_launch(void* const* d_in, const int* in_sizes, int n_in,
                              void* d_out, int out_size, void* d_ws, size_t ws_size,
                              hipStream_t stream)
{
    const float* visual  = (const float*)d_in[0];   // [B, NV, VDIM] fp32
    const float* textual = (const float*)d_in[1];   // [B, NT, TDIM] fp32
    const float* W       = (const float*)d_in[2];   // [TDIM, VDIM] fp32

    float* out  = (float*)d_out;                     // [B, NT, TDIM]
    float* attn = out + (size_t)BB * NT * TDIM;      // [B*H, NT, NV]

    const size_t VC_ELEMS = (size_t)BB * NV * TDIM;  // 16,777,216
    __bf16* vc_hi = (__bf16*)d_ws;
    __bf16* vc_lo = vc_hi + VC_ELEMS;
    __bf16* kT    = vc_lo + VC_ELEMS;                // ws total ~100.7 MB

    gemm1_kernel<<<dim3(TDIM / 128, (BB * NV) / 128), 256, 0, stream>>>(
        visual, W, vc_hi, vc_lo);
    transpose_kernel<<<dim3(NV / 64, DHEAD / 64, BB * HEADS), 256, 0, stream>>>(
        vc_hi, kT);
    attn_kernel<<<dim3(NT / 64, BB * HEADS), 256, 0, stream>>>(
        textual, vc_hi, vc_lo, kT, out, attn);
}